// Round 6
// baseline (480.768 us; speedup 1.0000x reference)
//
#include <hip/hip_runtime.h>

// RF grid-sample DAS beamforming, round 6.
// Shapes: d_tx[4,512,256] d_rx[128,512,256] apod[128,512,256] rf[4,128,3072] t0[4]
// out[4,512,256] fp32.
//
// Established by A/B (R1=96us best; R2=198, R3=144, R4=158, R5=126):
//  - Geometry: TPB=512, PXT=8, TILES=32, ESPLIT=16, tile-fast grid (XCD=tile%8
//    keeps the 16-way atomic updates per out line XCD-local). Any deviation
//    regressed (R2/R3/R4).
//  - bf16-pack + register-prefetch combo (R2..R5) correlates with +50 MB FETCH /
//    +33 MB WRITE / +30us at fixed geometry -> dropped entirely; back to fp32 LDS
//    (compiler emits ds_read2_b32 for the adjacent tap pair).
//  - R1 profile: HBM 1.3 TB/s (21%), VALU 15%, occ 39% -> limiter is the 128 MB
//    compulsory d_rx/apod stream running at poor efficiency (scalar dword loads,
//    drained at each e-barrier).
// THIS ROUND (one change): consecutive-pixel mapping so the d_rx/apod stream is
// float4 loads (16 B/lane, 4x fewer VMEM insts, 4x bytes in flight).
// Predict dur 96 -> 55-70us, hbm_gbps 1.3 -> 2.5-3.5 TB/s, FETCH/WRITE ~ R1.
//
// Data range: delays in [0,3070) => i0<=3069, i1<=3070 always in-range; (int)
// truncation == floor since delay >= 0.

#define A_N 4
#define E_N 128
#define S_N 3072
#define NPIX_N (512 * 256)
#define TPB 512
#define PXT 8
#define TILE (TPB * PXT)           // 4096 consecutive pixels per block
#define TILES (NPIX_N / TILE)      // 32
#define ESPLIT 16
#define EPB (E_N / ESPLIT)         // 8 elements per block
#define NF (A_N * S_N)             // 12288 floats = 48 KB
#define GRP (NF / 4 / TPB)         // 6 float4 staging groups per thread

__global__ __launch_bounds__(TPB, 4) void das_kernel(
    const float* __restrict__ d_tx, const float* __restrict__ d_rx,
    const float* __restrict__ apod, const float* __restrict__ rf,
    const float* __restrict__ t0,  float* __restrict__ out)
{
    __shared__ float lds_rf[NF];   // 48 KB, [A][S] fp32
    const int tid = threadIdx.x;
    const int px  = blockIdx.x * TILE + tid * PXT;  // 8 consecutive pixels/thread
    const int e0  = blockIdx.y * EPB;

    // Staging source offsets (rf element units; full addr = soff + e*S_N).
    int soff[GRP];
#pragma unroll
    for (int g = 0; g < GRP; ++g) {
        int idx = g * TPB + tid;            // float4 index in [0,3072)
        int a   = idx / (S_N / 4);          // 768 float4 per angle row
        int s4  = idx - a * (S_N / 4);
        soff[g] = a * (E_N * S_N) + s4 * 4;
    }

    float acc[A_N][PXT];
    float dta[A_N][PXT];
#pragma unroll
    for (int a = 0; a < A_N; ++a) {
        const float t0a = t0[a];
        const float4 v0 = *(const float4*)(d_tx + a * NPIX_N + px);
        const float4 v1 = *(const float4*)(d_tx + a * NPIX_N + px + 4);
        dta[a][0] = v0.x - t0a; dta[a][1] = v0.y - t0a;
        dta[a][2] = v0.z - t0a; dta[a][3] = v0.w - t0a;
        dta[a][4] = v1.x - t0a; dta[a][5] = v1.y - t0a;
        dta[a][6] = v1.z - t0a; dta[a][7] = v1.w - t0a;
#pragma unroll
        for (int k = 0; k < PXT; ++k) acc[a][k] = 0.0f;
    }

    for (int ei = 0; ei < EPB; ++ei) {
        const int e = e0 + ei;
        __syncthreads();   // previous iteration's gathers done before overwrite
        // Stage rf[0..3][e][:] into LDS (fp32, float4 chunks).
#pragma unroll
        for (int g = 0; g < GRP; ++g) {
            float4 v = *(const float4*)(rf + soff[g] + e * S_N);
            ((float4*)lds_rf)[g * TPB + tid] = v;
        }
        __syncthreads();

        // Stream d_rx/apod for this element as float4 (the round's one change).
        const float* __restrict__ drx_row = d_rx + (size_t)e * NPIX_N + px;
        const float* __restrict__ ap_row  = apod + (size_t)e * NPIX_N + px;
        const float4 dr0 = *(const float4*)(drx_row);
        const float4 dr1 = *(const float4*)(drx_row + 4);
        const float4 ap0 = *(const float4*)(ap_row);
        const float4 ap1 = *(const float4*)(ap_row + 4);
        float drx_k[PXT] = {dr0.x, dr0.y, dr0.z, dr0.w, dr1.x, dr1.y, dr1.z, dr1.w};
        float ap_k[PXT]  = {ap0.x, ap0.y, ap0.z, ap0.w, ap1.x, ap1.y, ap1.z, ap1.w};

#pragma unroll
        for (int k = 0; k < PXT; ++k) {
            const float drx = drx_k[k];
            const float ap  = ap_k[k];
#pragma unroll
            for (int a = 0; a < A_N; ++a) {
                float delay = dta[a][k] + drx;
                int i0 = (int)delay;                 // trunc == floor (delay >= 0)
                float w = delay - (float)i0;
                float v0 = lds_rf[a * S_N + i0];     // adjacent pair ->
                float v1 = lds_rf[a * S_N + i0 + 1]; //   ds_read2_b32
                acc[a][k] += ap * (v0 + w * (v1 - v0));
            }
        }
    }

#pragma unroll
    for (int a = 0; a < A_N; ++a)
#pragma unroll
        for (int k = 0; k < PXT; ++k)
            atomicAdd(&out[a * NPIX_N + px + k], acc[a][k]);
}

extern "C" void kernel_launch(void* const* d_in, const int* in_sizes, int n_in,
                              void* d_out, int out_size, void* d_ws, size_t ws_size,
                              hipStream_t stream) {
    const float* d_tx = (const float*)d_in[0];
    const float* d_rx = (const float*)d_in[1];
    const float* apod = (const float*)d_in[2];
    const float* rf   = (const float*)d_in[3];
    const float* t0   = (const float*)d_in[4];
    float* out = (float*)d_out;

    hipMemsetAsync(out, 0, (size_t)out_size * sizeof(float), stream);
    dim3 grid(TILES, ESPLIT);   // tile fast: same-tile blocks share an XCD (atomics local)
    das_kernel<<<grid, TPB, 0, stream>>>(d_tx, d_rx, apod, rf, t0, out);
}